// Round 5
// baseline (252.940 us; speedup 1.0000x reference)
//
#include <hip/hip_runtime.h>
#include <stdint.h>

// CIN forward, MI355X. R11b: resubmission of R11 (previous bench failed at
// the container level, not the kernel -- source audited: no divergent
// barriers, no OOB, LDS 18.9KB, est ~130 regs at launch_bounds(256,3)).
// R11: 32x32x16 f16 MFMA with A-operand (W) sharing.
// Model from R7-R10 counters: wall ~= MFMA_demand + VALU_demand (pipes barely
// overlap), so minimize their SUM. 32x32 shape keeps the 62us matrix floor;
// sharing one B-frag across 2 o-tile MFMAs halves bf-build VALU vs R9
// (4.5 -> 2.25 inst/MFMA). Addressing VALU cut: readfirstlane W bases +
// imm offsets, peeled tail (no wrap checks). R10 lesson: NO split-K acc and
// launch_bounds(256,3) (~170 reg headroom) -> no scratch spill
// (tripwire: WRITE_SIZE must drop back to ~1.6MB).
// Decomposition: wave = 2 o-tiles(64 rows) x 1 d-tile(32 cols); 4 waves =
// 1 batch; grid 1024. d-sum combines the 2 dt-waves via 1KB LDS psum.
// HP=140 kept (bank fix, 7.7M -> 2.5M conflict cycles, verified R10).

typedef __attribute__((ext_vector_type(8))) _Float16 f16x8;
typedef __attribute__((ext_vector_type(2))) _Float16 f16x2;
typedef __attribute__((ext_vector_type(4))) float f32x4;
typedef __attribute__((ext_vector_type(16))) float f32x16;
typedef __attribute__((ext_vector_type(4))) int i32x4;
typedef __attribute__((ext_vector_type(2))) int i32x2;

union AB {
  i32x4 i;
  f16x8 h;
  uint32_t u[4];
};
union AB2 {
  i32x2 i;
  uint32_t u[2];
};

static __device__ __forceinline__ uint32_t pkmul(uint32_t a, uint32_t b) {
  f16x2 r = __builtin_bit_cast(f16x2, a) * __builtin_bit_cast(f16x2, b);
  return __builtin_bit_cast(uint32_t, r);  // one v_pk_mul_f16
}
static __device__ __forceinline__ uint32_t pkcvt(float a, float b) {
  return __builtin_bit_cast(uint32_t, __builtin_amdgcn_cvt_pkrtz(a, b));
}

#define HP 140  // hT row: 128 ch + 12 pad (280B: 70 dw = 6 mod 32 -> 16 banks)

__global__ __launch_bounds__(256, 3) void cin_main(
    const float* __restrict__ x, const uint16_t* __restrict__ wp,
    const float* __restrict__ bias0, const float* __restrict__ bias1,
    const float* __restrict__ bias2, float* __restrict__ out) {
  __shared__ __align__(16) uint16_t hT[64][HP];  // [d][chan] fp16, one batch
  __shared__ float psum[2][128];                 // [dt][o] d-sum partials

  const int tid = threadIdx.x;
  const int w = tid >> 6, lane = tid & 63;
  const int og = w & 1;     // o-group: o-tiles {2og, 2og+1}
  const int dt = w >> 1;    // d-tile (0: d=0..31, 1: d=32..63)
  const int hi = lane >> 5;   // A/B k-half; C row bit (4*hi)
  const int l31 = lane & 31;  // A row (o mod 32); B/C col (d mod 32)
  const int lane8 = lane * 8;
  const int b = blockIdx.x;   // one batch per block

  // ---- stage x -> hT[d][m] fp16 (layer-0 h == x; 32 channels)
  for (int e = tid; e < 2048; e += 256) {
    int m = e >> 6, d = e & 63;
    hT[d][m] =
        __builtin_bit_cast(uint16_t, (_Float16)x[(size_t)b * 2048 + m * 64 + d]);
  }
  __syncthreads();

  const int drow = dt * 32 + l31;  // this wave's d row in hT

  // ---- x B-frags (loop-invariant): xf[s].j = x[m=s*16+hi*8+j][d=drow]
  // b64 pairs (row stride 280B is 8B- but not 16B-aligned)
  AB xf[2];
#pragma unroll
  for (int s = 0; s < 2; ++s) {
    AB2 lo = *(const AB2*)&hT[drow][s * 16 + hi * 8];
    AB2 hi4 = *(const AB2*)&hT[drow][s * 16 + hi * 8 + 4];
    xf[s].u[0] = lo.u[0];
    xf[s].u[1] = lo.u[1];
    xf[s].u[2] = hi4.u[0];
    xf[s].u[3] = hi4.u[1];
  }

  f32x16 acc[2];  // [ot'] : 2 chains, one per local o-tile

#pragma unroll
  for (int L = 0; L < 3; ++L) {
    const int Kch = (L == 0) ? 32 : 128;
    const uint16_t* wl = (L == 0) ? wp : (L == 1) ? wp + 131072 : wp + 655360;
    const float* bias = (L == 0) ? bias0 : (L == 1) ? bias1 : bias2;

    // W frag (ot, c, s) at ((ot*Kch + c)*2 + s)*512 + lane*8 elems.
    // Wave-uniform bases (readfirstlane -> SGPR), per-load imm offsets.
    const uint16_t* pb0 =
        wl + ((size_t)__builtin_amdgcn_readfirstlane((og * 2 + 0) * Kch) << 10);
    const uint16_t* pb1 =
        wl + ((size_t)__builtin_amdgcn_readfirstlane((og * 2 + 1) * Kch) << 10);

#pragma unroll
    for (int o2 = 0; o2 < 2; ++o2)
#pragma unroll
      for (int r = 0; r < 16; ++r) acc[o2][r] = 0.f;

    AB wbuf[2][2][2][2];  // [slot][cc][s][ot'] : 16 AB = 64 VGPRs
    uint32_t hvA, hvB;

    auto loadSlot = [&](int sl, int c) {
#pragma unroll
      for (int cc = 0; cc < 2; ++cc)
#pragma unroll
        for (int s = 0; s < 2; ++s) {
          wbuf[sl][cc][s][0].i =
              *(const i32x4*)(pb0 + ((c + cc) << 10) + (s << 9) + lane8);
          wbuf[sl][cc][s][1].i =
              *(const i32x4*)(pb1 + ((c + cc) << 10) + (s << 9) + lane8);
        }
    };
    auto loadHv = [&](uint32_t& hv, int c) {
      hv = *(const uint32_t*)&hT[drow][c];  // channels c, c+1
    };
    // one call = 2 channels x 2 k-slices x 2 o-tiles = 8 MFMAs.
    // bf shared across the 2 o-tile MFMAs: 2.25 VALU/MFMA.
    auto compute2 = [&](const AB (&wb)[2][2][2], uint32_t hv) {
#pragma unroll
      for (int cc = 0; cc < 2; ++cc) {
        uint32_t hd = __builtin_amdgcn_perm(hv, hv,
                                            cc ? 0x03020302u : 0x01000100u);
#pragma unroll
        for (int s = 0; s < 2; ++s) {
          AB bf;  // B: P[k=(c+cc)*32+s*16+hi*8+j][d] = h[c+cc,d]*x[m,d]
#pragma unroll
          for (int k = 0; k < 4; ++k) bf.u[k] = pkmul(hd, xf[s].u[k]);
          acc[0] = __builtin_amdgcn_mfma_f32_32x32x16_f16(wb[cc][s][0].h, bf.h,
                                                          acc[0], 0, 0, 0);
          acc[1] = __builtin_amdgcn_mfma_f32_32x32x16_f16(wb[cc][s][1].h, bf.h,
                                                          acc[1], 0, 0, 0);
        }
      }
    };

    // prologue: slots hold channel-pairs 0 and 2; hvA holds pair 0
    loadSlot(0, 0);
    loadSlot(1, 2);
    loadHv(hvA, 0);

    // main loop peeled so prefetches never go out of range (no wrap checks)
#pragma unroll 1
    for (int c0 = 0; c0 < Kch - 4; c0 += 4) {
      loadHv(hvB, c0 + 2);
      compute2(wbuf[0], hvA);         // consume pair c0 ...
      loadSlot(0, c0 + 4);            // ... THEN reload slot 0 (pair c0+4)
      __builtin_amdgcn_sched_barrier(0);
      loadHv(hvA, c0 + 4);
      compute2(wbuf[1], hvB);         // consume pair c0+2 ...
      loadSlot(1, c0 + 6);            // ... THEN reload slot 1 (pair c0+6)
      __builtin_amdgcn_sched_barrier(0);
    }
    // tail: pairs Kch-4 (slot 0) and Kch-2 (slot 1); hvA holds Kch-4
    loadHv(hvB, Kch - 2);
    compute2(wbuf[0], hvA);
    compute2(wbuf[1], hvB);

    // ---- bias + ReLU. C layout (32x32): col d = drow,
    // row o = og*64 + o2*32 + (r&3) + 8*(r>>2) + 4*hi
#pragma unroll
    for (int o2 = 0; o2 < 2; ++o2)
#pragma unroll
      for (int rg = 0; rg < 4; ++rg) {
        f32x4 bv = *(const f32x4*)(bias + og * 64 + o2 * 32 + 8 * rg + 4 * hi);
#pragma unroll
        for (int rr = 0; rr < 4; ++rr)
          acc[o2][4 * rg + rr] = fmaxf(acc[o2][4 * rg + rr] + bv[rr], 0.f);
      }

    if (L < 2) {
      __syncthreads();  // all waves done READING hT before overwrite
#pragma unroll
      for (int o2 = 0; o2 < 2; ++o2)
#pragma unroll
        for (int rg = 0; rg < 4; ++rg) {
          uint2 pk;  // next-layer h channels, 4 consecutive rows
          pk.x = pkcvt(acc[o2][4 * rg + 0], acc[o2][4 * rg + 1]);
          pk.y = pkcvt(acc[o2][4 * rg + 2], acc[o2][4 * rg + 3]);
          *(uint2*)&hT[drow][og * 64 + o2 * 32 + 8 * rg + 4 * hi] = pk;
        }
    }

    // ---- d-sum partial: xor-reduce the 32 l31 lanes, stash per-dt in LDS
#pragma unroll
    for (int o2 = 0; o2 < 2; ++o2)
#pragma unroll
      for (int rg = 0; rg < 4; ++rg)
#pragma unroll
        for (int rr = 0; rr < 4; ++rr) {
          float s = acc[o2][4 * rg + rr];
          s += __shfl_xor(s, 1);
          s += __shfl_xor(s, 2);
          s += __shfl_xor(s, 4);
          s += __shfl_xor(s, 8);
          s += __shfl_xor(s, 16);
          if (l31 == 0)
            psum[dt][og * 64 + o2 * 32 + 8 * rg + 4 * hi + rr] = s;
        }
    __syncthreads();  // psum (and hT writeback) visible
    if (tid < 128)
      out[(size_t)b * 384 + L * 128 + tid] = psum[0][tid] + psum[1][tid];

    if (L < 2) __syncthreads();  // out-read of psum done before next layer
  }
}

// Pack for 32x32x16 A layout: frag (ot,c,s) elem lane*8+j holds
// W[o = ot*32 + (lane&31)][k = c*32 + s*16 + (lane>>5)*8 + j].
// Reads stay coalesced along k (thread = (o,kq), 8 consecutive floats).
// (unchanged from R9/R10 -- verified correct)
__global__ void pack_w_all(const float* __restrict__ W0, const float* __restrict__ W1,
                           const float* __restrict__ W2, uint16_t* __restrict__ Wp) {
  int blk = blockIdx.x;
  const float* W;
  uint16_t* dst;
  int kshift;  // Kch = 1<<kshift, K = 1<<(kshift+5)
  if (blk < 64)       { W = W0; dst = Wp;          kshift = 5; }
  else if (blk < 320) { W = W1; dst = Wp + 131072; kshift = 7; blk -= 64; }
  else                { W = W2; dst = Wp + 655360; kshift = 7; blk -= 320; }
  int idx = blk * 256 + threadIdx.x;
  int Kq = 1 << (kshift + 2);        // K/8
  int o = idx >> (kshift + 2);
  int kq = idx & (Kq - 1);
  int c = kq >> 2, s = (kq >> 1) & 1, hi = kq & 1;
  int ot = o >> 5, li = o & 31;
  const float* src = W + ((size_t)o << (kshift + 5)) + kq * 8;
  uint4 val;
  val.x = pkcvt(src[0], src[1]);
  val.y = pkcvt(src[2], src[3]);
  val.z = pkcvt(src[4], src[5]);
  val.w = pkcvt(src[6], src[7]);
  size_t d16 = ((((size_t)(ot << kshift) + c) * 2 + s) << 9) + (hi << 8) + (li << 3);
  *(uint4*)(dst + d16) = val;
}

extern "C" void kernel_launch(void* const* d_in, const int* in_sizes, int n_in,
                              void* d_out, int out_size, void* d_ws, size_t ws_size,
                              hipStream_t stream) {
  (void)in_sizes; (void)n_in; (void)out_size; (void)ws_size;
  const float* x  = (const float*)d_in[0];
  const float* W0 = (const float*)d_in[1];
  const float* b0 = (const float*)d_in[2];
  const float* W1 = (const float*)d_in[3];
  const float* b1 = (const float*)d_in[4];
  const float* W2 = (const float*)d_in[5];
  const float* b2 = (const float*)d_in[6];
  uint16_t* wpacked = (uint16_t*)d_ws;  // 2.25 MB of ws

  hipLaunchKernelGGL(pack_w_all, dim3(576), dim3(256), 0, stream, W0, W1, W2, wpacked);
  hipLaunchKernelGGL(cin_main, dim3(1024), dim3(256), 0, stream,
                     x, wpacked, b0, b1, b2, (float*)d_out);
}

// Round 6
// 200.616 us; speedup vs baseline: 1.2608x; 1.2608x over previous
//
#include <hip/hip_runtime.h>
#include <stdint.h>

// CIN forward, MI355X. R12: three-pipe demand model (fits R7/R8/R9/R11 to 3%):
//   wall ~= MFMA_demand + VMEM_demand + VALU_demand
//   MFMA: 61us floor at 32x32x16. VMEM: each dwordx4 W-load = 1KB/wave ~16cyc
//   of per-CU L1 return; R9 = 61us (W once/batch), R11 = 123us (W 2x/block!).
// Fix: batch-amortize W. Wave = (1 o-tile x 2 d-tiles x 2 batches):
//   one W-frag load feeds 4 MFMAs -> W read once per 2-batch block -> 30us.
//   acc[b][dt] = 4 chains (RAW dist 4). VALU back to R9's 4.5/MFMA (~17-30us).
// 256-thr blocks (4 waves = 4 o-tiles), grid 512. Regs: acc 64(AGPR) + xf 32
// + wbuf 32 + hv 8 + addr ~= 156 unified < 170 @ bounds(256,3) -> no spill
// (tripwire: WRITE_SIZE ~1.5MB). HP=140 bank fix kept. Fragment layouts
// unchanged from correctness-verified R9/R11.

typedef __attribute__((ext_vector_type(8))) _Float16 f16x8;
typedef __attribute__((ext_vector_type(2))) _Float16 f16x2;
typedef __attribute__((ext_vector_type(4))) float f32x4;
typedef __attribute__((ext_vector_type(16))) float f32x16;
typedef __attribute__((ext_vector_type(4))) int i32x4;
typedef __attribute__((ext_vector_type(2))) int i32x2;

union AB {
  i32x4 i;
  f16x8 h;
  uint32_t u[4];
};
union AB2 {
  i32x2 i;
  uint32_t u[2];
};

static __device__ __forceinline__ uint32_t pkmul(uint32_t a, uint32_t b) {
  f16x2 r = __builtin_bit_cast(f16x2, a) * __builtin_bit_cast(f16x2, b);
  return __builtin_bit_cast(uint32_t, r);  // one v_pk_mul_f16
}
static __device__ __forceinline__ uint32_t pkcvt(float a, float b) {
  return __builtin_bit_cast(uint32_t, __builtin_amdgcn_cvt_pkrtz(a, b));
}

#define HP 140  // hT row: 128 ch + 12 pad (280B: 70 dw = 6 mod 32 -> 16 banks)

__global__ __launch_bounds__(256, 3) void cin_main(
    const float* __restrict__ x, const uint16_t* __restrict__ wp,
    const float* __restrict__ bias0, const float* __restrict__ bias1,
    const float* __restrict__ bias2, float* __restrict__ out) {
  __shared__ __align__(16) uint16_t hT[2][64][HP];  // [batch][d][chan] fp16

  const int tid = threadIdx.x;
  const int ot = tid >> 6, lane = tid & 63;  // wave = o-tile index (0..3)
  const int hi = lane >> 5;   // A/B k-half; C row bit (4*hi)
  const int l31 = lane & 31;  // A row (o mod 32); B/C col (d mod 32)
  const int lane8 = lane * 8;
  const int bb = blockIdx.x * 2;  // two batches per block

  // ---- stage x -> hT[p][d][m] fp16 (layer-0 h == x; 32 channels)
  for (int e = tid; e < 4096; e += 256) {
    int p = e >> 11, m = (e >> 6) & 31, d = e & 63;
    hT[p][d][m] =
        __builtin_bit_cast(uint16_t, (_Float16)x[(size_t)(bb + p) * 2048 + m * 64 + d]);
  }
  __syncthreads();

  // ---- x B-frags (loop-invariant; x is the base field for ALL layers):
  // xf[b][dt][s].j = x_b[m=s*16+hi*8+j][d=dt*32+l31]; b64 pairs (280B rows
  // are 8B- but not 16B-aligned)
  AB xf[2][2][2];
#pragma unroll
  for (int b2 = 0; b2 < 2; ++b2)
#pragma unroll
    for (int dt = 0; dt < 2; ++dt)
#pragma unroll
      for (int s = 0; s < 2; ++s) {
        AB2 lo = *(const AB2*)&hT[b2][dt * 32 + l31][s * 16 + hi * 8];
        AB2 hi4 = *(const AB2*)&hT[b2][dt * 32 + l31][s * 16 + hi * 8 + 4];
        xf[b2][dt][s].u[0] = lo.u[0];
        xf[b2][dt][s].u[1] = lo.u[1];
        xf[b2][dt][s].u[2] = hi4.u[0];
        xf[b2][dt][s].u[3] = hi4.u[1];
      }

  f32x16 acc[2][2];  // [batch][dt] : 4 independent chains

#pragma unroll
  for (int L = 0; L < 3; ++L) {
    const int Kch = (L == 0) ? 32 : 128;
    const uint16_t* wl = (L == 0) ? wp : (L == 1) ? wp + 131072 : wp + 655360;
    const float* bias = (L == 0) ? bias0 : (L == 1) ? bias1 : bias2;

    // W frag (ot, c, s) at ((ot*Kch + c)*2 + s)*512 + lane*8 elems.
    // Wave-uniform base in SGPR via readfirstlane.
    const uint16_t* pb =
        wl + ((size_t)__builtin_amdgcn_readfirstlane(ot * Kch) << 10);

#pragma unroll
    for (int b2 = 0; b2 < 2; ++b2)
#pragma unroll
      for (int dt = 0; dt < 2; ++dt)
#pragma unroll
        for (int r = 0; r < 16; ++r) acc[b2][dt][r] = 0.f;

    AB wbuf[2][2][2];  // [slot][cc][s] : 8 AB = 32 VGPRs, depth-2 rotation
    uint32_t hvA[2][2], hvB[2][2];  // [batch][dt]

    auto loadSlot = [&](int sl, int c) {
#pragma unroll
      for (int cc = 0; cc < 2; ++cc)
#pragma unroll
        for (int s = 0; s < 2; ++s)
          wbuf[sl][cc][s].i =
              *(const i32x4*)(pb + ((c + cc) << 10) + (s << 9) + lane8);
    };
    auto loadHv = [&](uint32_t (&hv)[2][2], int c) {
#pragma unroll
      for (int b2 = 0; b2 < 2; ++b2)
#pragma unroll
        for (int dt = 0; dt < 2; ++dt)
          hv[b2][dt] = *(const uint32_t*)&hT[b2][dt * 32 + l31][c];  // ch c,c+1
    };
    // one step = 2 channels x 2 k-slices x 2 batches x 2 d-tiles = 16 MFMAs.
    // One W-frag feeds 4 MFMAs (VMEM 0.25 loads/MFMA); chains at RAW dist 4.
    auto computeStep = [&](const AB (&wb)[2][2], const uint32_t (&hv)[2][2]) {
#pragma unroll
      for (int cc = 0; cc < 2; ++cc) {
        uint32_t hd[2][2];
#pragma unroll
        for (int b2 = 0; b2 < 2; ++b2)
#pragma unroll
          for (int dt = 0; dt < 2; ++dt)
            hd[b2][dt] = __builtin_amdgcn_perm(
                hv[b2][dt], hv[b2][dt], cc ? 0x03020302u : 0x01000100u);
#pragma unroll
        for (int s = 0; s < 2; ++s)
#pragma unroll
          for (int b2 = 0; b2 < 2; ++b2)
#pragma unroll
            for (int dt = 0; dt < 2; ++dt) {
              AB bf;  // B: P[k=(c+cc)*32+s*16+hi*8+j][d] = h[c+cc,d]*x[m,d]
#pragma unroll
              for (int k = 0; k < 4; ++k)
                bf.u[k] = pkmul(hd[b2][dt], xf[b2][dt][s].u[k]);
              acc[b2][dt] = __builtin_amdgcn_mfma_f32_32x32x16_f16(
                  wb[cc][s].h, bf.h, acc[b2][dt], 0, 0, 0);
            }
      }
    };

    // prologue: slots hold channel-pairs 0 and 2; hvA holds pair 0
    loadSlot(0, 0);
    loadSlot(1, 2);
    loadHv(hvA, 0);

    // main loop peeled so prefetches never go out of range (no wrap checks)
#pragma unroll 1
    for (int c0 = 0; c0 < Kch - 4; c0 += 4) {
      loadHv(hvB, c0 + 2);
      computeStep(wbuf[0], hvA);      // consume pair c0 ...
      loadSlot(0, c0 + 4);            // ... THEN reload slot 0 (pair c0+4)
      __builtin_amdgcn_sched_barrier(0);
      loadHv(hvA, c0 + 4);
      computeStep(wbuf[1], hvB);      // consume pair c0+2 ...
      loadSlot(1, c0 + 6);            // ... THEN reload slot 1 (pair c0+6)
      __builtin_amdgcn_sched_barrier(0);
    }
    // tail: pairs Kch-4 (slot 0) and Kch-2 (slot 1); hvA holds Kch-4
    loadHv(hvB, Kch - 2);
    computeStep(wbuf[0], hvA);
    computeStep(wbuf[1], hvB);

    // ---- bias + ReLU. C layout (32x32): col d = dt*32+l31,
    // row o = ot*32 + (r&3) + 8*(r>>2) + 4*hi
#pragma unroll
    for (int rg = 0; rg < 4; ++rg) {
      f32x4 bv = *(const f32x4*)(bias + ot * 32 + 8 * rg + 4 * hi);
#pragma unroll
      for (int b2 = 0; b2 < 2; ++b2)
#pragma unroll
        for (int dt = 0; dt < 2; ++dt)
#pragma unroll
          for (int rr = 0; rr < 4; ++rr)
            acc[b2][dt][4 * rg + rr] =
                fmaxf(acc[b2][dt][4 * rg + rr] + bv[rr], 0.f);
    }

    if (L < 2) {
      __syncthreads();  // all waves done READING hT before overwrite
#pragma unroll
      for (int b2 = 0; b2 < 2; ++b2)
#pragma unroll
        for (int dt = 0; dt < 2; ++dt)
#pragma unroll
          for (int rg = 0; rg < 4; ++rg) {
            uint2 pk;  // next-layer h channels, 4 consecutive rows
            pk.x = pkcvt(acc[b2][dt][4 * rg + 0], acc[b2][dt][4 * rg + 1]);
            pk.y = pkcvt(acc[b2][dt][4 * rg + 2], acc[b2][dt][4 * rg + 3]);
            *(uint2*)&hT[b2][dt * 32 + l31][ot * 32 + 8 * rg + 4 * hi] = pk;
          }
    }

    // ---- d-sum: acc[.][0]+acc[.][1] (d and d+32), xor-reduce 32 l31 lanes
#pragma unroll
    for (int b2 = 0; b2 < 2; ++b2)
#pragma unroll
      for (int rg = 0; rg < 4; ++rg) {
        f32x4 s4;
#pragma unroll
        for (int rr = 0; rr < 4; ++rr) {
          float s = acc[b2][0][4 * rg + rr] + acc[b2][1][4 * rg + rr];
          s += __shfl_xor(s, 1);
          s += __shfl_xor(s, 2);
          s += __shfl_xor(s, 4);
          s += __shfl_xor(s, 8);
          s += __shfl_xor(s, 16);
          s4[rr] = s;
        }
        if (l31 == 0)
          *(f32x4*)(out + (size_t)(bb + b2) * 384 + L * 128 + ot * 32 +
                    8 * rg + 4 * hi) = s4;
      }

    if (L < 2) __syncthreads();  // hT writes visible before next K-loop
  }
}

// Pack for 32x32x16 A layout: frag (ot,c,s) elem lane*8+j holds
// W[o = ot*32 + (lane&31)][k = c*32 + s*16 + (lane>>5)*8 + j].
// Reads stay coalesced along k (thread = (o,kq), 8 consecutive floats).
// (unchanged from R9/R10/R11 -- verified correct)
__global__ void pack_w_all(const float* __restrict__ W0, const float* __restrict__ W1,
                           const float* __restrict__ W2, uint16_t* __restrict__ Wp) {
  int blk = blockIdx.x;
  const float* W;
  uint16_t* dst;
  int kshift;  // Kch = 1<<kshift, K = 1<<(kshift+5)
  if (blk < 64)       { W = W0; dst = Wp;          kshift = 5; }
  else if (blk < 320) { W = W1; dst = Wp + 131072; kshift = 7; blk -= 64; }
  else                { W = W2; dst = Wp + 655360; kshift = 7; blk -= 320; }
  int idx = blk * 256 + threadIdx.x;
  int Kq = 1 << (kshift + 2);        // K/8
  int o = idx >> (kshift + 2);
  int kq = idx & (Kq - 1);
  int c = kq >> 2, s = (kq >> 1) & 1, hi = kq & 1;
  int ot = o >> 5, li = o & 31;
  const float* src = W + ((size_t)o << (kshift + 5)) + kq * 8;
  uint4 val;
  val.x = pkcvt(src[0], src[1]);
  val.y = pkcvt(src[2], src[3]);
  val.z = pkcvt(src[4], src[5]);
  val.w = pkcvt(src[6], src[7]);
  size_t d16 = ((((size_t)(ot << kshift) + c) * 2 + s) << 9) + (hi << 8) + (li << 3);
  *(uint4*)(dst + d16) = val;
}

extern "C" void kernel_launch(void* const* d_in, const int* in_sizes, int n_in,
                              void* d_out, int out_size, void* d_ws, size_t ws_size,
                              hipStream_t stream) {
  (void)in_sizes; (void)n_in; (void)out_size; (void)ws_size;
  const float* x  = (const float*)d_in[0];
  const float* W0 = (const float*)d_in[1];
  const float* b0 = (const float*)d_in[2];
  const float* W1 = (const float*)d_in[3];
  const float* b1 = (const float*)d_in[4];
  const float* W2 = (const float*)d_in[5];
  const float* b2 = (const float*)d_in[6];
  uint16_t* wpacked = (uint16_t*)d_ws;  // 2.25 MB of ws

  hipLaunchKernelGGL(pack_w_all, dim3(576), dim3(256), 0, stream, W0, W1, W2, wpacked);
  hipLaunchKernelGGL(cin_main, dim3(512), dim3(256), 0, stream,
                     x, wpacked, b0, b1, b2, (float*)d_out);
}